// Round 1
// baseline (90.412 us; speedup 1.0000x reference)
//
#include <hip/hip_runtime.h>

// AdderNet 2D: out[n,f,i,j] = -sum_{c,kh,kw} |xpad[n,c,i+kh,j+kw] - W[f,c,kh,kw]|
// x: [16,32,56,56] f32, W: [64,32,3,3] f32, out: [16,64,56,56] f32. PAD=1, STRIDE=1.

#define N_    16
#define C_    32
#define H_    56
#define F_    64
#define KDIM  288      // C_*9
#define CCH   16       // channels per LDS chunk
#define NCH   (C_/CCH) // 2 chunks
#define ROWS  2        // output rows per block
#define XROWS (ROWS+2) // with halo
#define XSTR  58       // padded row width (56 + 2 halo cols)
#define SPT   7        // spatial cols per thread
#define FPT   4        // filters per thread
#define TPB   256

__global__ __launch_bounds__(TPB, 2)
void adder2d_kernel(const float* __restrict__ x,
                    const float* __restrict__ w,
                    float* __restrict__ out) {
    __shared__ float xs[CCH][XROWS][XSTR];   // 3712 floats = 14.8 KB
    __shared__ float wt[CCH * 9][F_];        // 9216 floats = 36.9 KB (transposed: [k][f])

    const int tid = threadIdx.x;
    const int bid = blockIdx.x;
    const int n   = bid / 28;
    const int rt  = bid % 28;
    const int i0  = rt * ROWS;          // first output row of this block

    // thread -> (filter group, spatial group)
    const int fg = tid >> 4;            // 0..15
    const int sg = tid & 15;            // 0..15
    const int ir = sg >> 3;             // 0..1  (which of the 2 output rows)
    const int j0 = (sg & 7) * SPT;      // 0,7,...,49
    const int f0 = fg * FPT;            // 0,4,...,60

    float acc[FPT][SPT];
    #pragma unroll
    for (int f = 0; f < FPT; ++f)
        #pragma unroll
        for (int s = 0; s < SPT; ++s) acc[f][s] = 0.0f;

    for (int ch = 0; ch < NCH; ++ch) {
        const int c0 = ch * CCH;
        __syncthreads();  // protect previous chunk's LDS reads before overwrite

        // ---- stage x chunk with zero halo (padded coords: xp[r][c], r,c in [0,58)) ----
        for (int e = tid; e < CCH * XROWS * XSTR; e += TPB) {
            const int c  = e / (XROWS * XSTR);
            const int r  = (e / XSTR) % XROWS;
            const int cp = e % XSTR;
            const int rp = i0 + r;      // padded row index
            float v = 0.0f;
            if (rp >= 1 && rp <= H_ && cp >= 1 && cp <= H_)
                v = x[((n * C_ + c0 + c) * H_ + (rp - 1)) * H_ + (cp - 1)];
            xs[c][r][cp] = v;
        }
        // ---- stage W chunk transposed: wt[kk][f] = W[f][c0*9 + kk] ----
        for (int e = tid; e < CCH * 9 * F_; e += TPB) {
            const int kk = e >> 6;
            const int f  = e & 63;
            wt[kk][f] = w[f * KDIM + c0 * 9 + kk];
        }
        __syncthreads();

        // ---- compute: 16 channels x 3 kh x (9-float x window slid over 3 kw) ----
        for (int c = 0; c < CCH; ++c) {
            #pragma unroll
            for (int kh = 0; kh < 3; ++kh) {
                float xw[SPT + 2];
                #pragma unroll
                for (int t = 0; t < SPT + 2; ++t)
                    xw[t] = xs[c][ir + kh][j0 + t];
                #pragma unroll
                for (int kw = 0; kw < 3; ++kw) {
                    const float4 wv = *(const float4*)&wt[c * 9 + kh * 3 + kw][f0];
                    const float wf[FPT] = {wv.x, wv.y, wv.z, wv.w};
                    #pragma unroll
                    for (int f = 0; f < FPT; ++f)
                        #pragma unroll
                        for (int s = 0; s < SPT; ++s)
                            acc[f][s] += fabsf(xw[s + kw] - wf[f]);
                }
            }
        }
    }

    // ---- epilogue: out = -acc ----
    const int orow = i0 + ir;
    #pragma unroll
    for (int f = 0; f < FPT; ++f) {
        float* op = &out[((n * F_ + f0 + f) * H_ + orow) * H_ + j0];
        #pragma unroll
        for (int s = 0; s < SPT; ++s) op[s] = -acc[f][s];
    }
}

extern "C" void kernel_launch(void* const* d_in, const int* in_sizes, int n_in,
                              void* d_out, int out_size, void* d_ws, size_t ws_size,
                              hipStream_t stream) {
    const float* x = (const float*)d_in[0];
    const float* w = (const float*)d_in[1];
    float* out = (float*)d_out;
    adder2d_kernel<<<dim3(N_ * 28), dim3(TPB), 0, stream>>>(x, w, out);
}